// Round 1
// baseline (9216.908 us; speedup 1.0000x reference)
//
#include <hip/hip_runtime.h>
#include <hip/hip_bf16.h>

// CustomLSTM: B=128, T=1024, D=256, U=256, fp32 in/out.
// Strategy:
//  - pack_kernel: repack U* (and W*) fp32 -> bf16 MFMA B-fragments in d_ws.
//  - proj_kernel: zx[m][u][4gates] (bf16) = x @ W* via mfma_f32_16x16x32_bf16.
//  - lstm_scan:   8 blocks x 16 batches, per-batch-independent recurrence.
//                 Per step: stream 512KB of U-fragments from L2, 512 MFMAs,
//                 in-lane fp32 gate elementwise (C-layout puts all 4 gates of
//                 one (b,u) in the same lane), restage h via 8KB LDS.
// No inter-block communication anywhere.

#define B_ 128
#define T_ 1024
#define D_ 256
#define U_ 256

using short8  = __attribute__((ext_vector_type(8))) short;   // 8 bf16 (4 VGPRs)
using float4v = __attribute__((ext_vector_type(4))) float;   // 4 fp32 acc

__device__ inline unsigned short f2bf(float f) {
    unsigned int u = __float_as_uint(f);
    unsigned int r = (u + 0x7FFFu + ((u >> 16) & 1u)) >> 16;
    return (unsigned short)r;
}
__device__ inline float bf2f(unsigned int v) { return __uint_as_float(v << 16); }
__device__ inline float sigm(float z)  { return 1.0f / (1.0f + __expf(-z)); }
__device__ inline float tanh_f(float z){ float e = __expf(2.0f * z); return 1.0f - 2.0f / (e + 1.0f); }

// ---------------------------------------------------------------------------
// Pack 8 matrices [256][256] fp32 (row k, col u) into bf16 MFMA B-fragments.
// Pack layout: chunk = (w*8 + ks)*8 + g*2 + h ; chunk = 512 shorts (64 lanes x 8).
// Lane l of chunk holds  M[k = ks*32 + (l>>4)*8 + j][u = w*32 + h*16 + (l&15)].
// pack0 (offset 0 shorts)      = Uf,Ui,Uc,Uo   (recurrent)
// pack1 (offset 262144 shorts) = Wf,Wi,Wc,Wo   (input proj)
// ---------------------------------------------------------------------------
__global__ __launch_bounds__(256) void pack_kernel(
    const float* __restrict__ Uf, const float* __restrict__ Ui,
    const float* __restrict__ Uc, const float* __restrict__ Uo,
    const float* __restrict__ Wf, const float* __restrict__ Wi,
    const float* __restrict__ Wc, const float* __restrict__ Wo,
    short* __restrict__ ws)
{
    int q = blockIdx.x * 256 + threadIdx.x;      // 0..65535
    int p     = q >> 15;                          // 0: U-pack, 1: W-pack
    int rem   = q & 32767;
    int chunk = rem >> 6;                         // 0..511
    int l     = rem & 63;
    int c8 = chunk & 7;
    int g  = c8 >> 1;
    int h  = c8 & 1;
    int ks = (chunk >> 3) & 7;
    int w  = chunk >> 6;

    const float* mats[8] = {Uf, Ui, Uc, Uo, Wf, Wi, Wc, Wo};
    const float* M = mats[p * 4 + g];

    int u = w * 32 + h * 16 + (l & 15);
    int k = ks * 32 + ((l >> 4) << 3);
    const float* s = M + (size_t)k * 256 + u;

    short8 fr;
#pragma unroll
    for (int j = 0; j < 8; ++j) fr[j] = (short)f2bf(s[(size_t)j * 256]);

    short* dst = ws + (size_t)p * 262144 + (size_t)chunk * 512 + l * 8;
    *reinterpret_cast<short8*>(dst) = fr;
}

// ---------------------------------------------------------------------------
// proj: zx[m][u][g] (bf16, g minor) = sum_k x[m][k] * W_g[k][u]
// M-tile = 64 rows per block; streams W-pack fragments straight from L2.
// ---------------------------------------------------------------------------
__global__ __launch_bounds__(512, 2) void proj_kernel(
    const float* __restrict__ x, const short* __restrict__ wpack,
    short* __restrict__ zx)
{
    __shared__ short aF[4 * 8 * 512];  // 4 M-sub x 8 ks chunks (32KB)
    const int tid = threadIdx.x;
    const int w = tid >> 6, l = tid & 63;
    const long m0 = (long)blockIdx.x * 64;

    // stage A fragments: x rows m0..m0+63, bf16
#pragma unroll
    for (int rep = 0; rep < 4; ++rep) {
        int slot = tid + rep * 512;      // 0..2047
        int ms = slot >> 9;
        int rem = slot & 511;
        int ks = rem >> 6;
        int ll = rem & 63;
        long mm = m0 + ms * 16 + (ll & 15);
        int k = ks * 32 + ((ll >> 4) << 3);
        const float* s = x + (size_t)mm * 256 + k;
        float4 v0 = *reinterpret_cast<const float4*>(s);
        float4 v1 = *reinterpret_cast<const float4*>(s + 4);
        short8 fr;
        fr[0] = (short)f2bf(v0.x); fr[1] = (short)f2bf(v0.y);
        fr[2] = (short)f2bf(v0.z); fr[3] = (short)f2bf(v0.w);
        fr[4] = (short)f2bf(v1.x); fr[5] = (short)f2bf(v1.y);
        fr[6] = (short)f2bf(v1.z); fr[7] = (short)f2bf(v1.w);
        *reinterpret_cast<short8*>(&aF[(ms * 8 + ks) * 512 + ll * 8]) = fr;
    }
    __syncthreads();

    float4v acc[4][8];
#pragma unroll
    for (int ms = 0; ms < 4; ++ms)
#pragma unroll
        for (int c8 = 0; c8 < 8; ++c8) acc[ms][c8] = (float4v){0.f, 0.f, 0.f, 0.f};

    const short* base = wpack + (size_t)w * 64 * 512;
#pragma unroll
    for (int ks = 0; ks < 8; ++ks) {
        short8 a[4];
#pragma unroll
        for (int ms = 0; ms < 4; ++ms)
            a[ms] = *reinterpret_cast<const short8*>(&aF[(ms * 8 + ks) * 512 + l * 8]);
#pragma unroll
        for (int c8 = 0; c8 < 8; ++c8) {
            short8 bfr = *reinterpret_cast<const short8*>(base + (size_t)(ks * 8 + c8) * 512 + l * 8);
#pragma unroll
            for (int ms = 0; ms < 4; ++ms)
                acc[ms][c8] = __builtin_amdgcn_mfma_f32_16x16x32_bf16(a[ms], bfr, acc[ms][c8], 0, 0, 0);
        }
    }

    // write zx: 4 gates packed per (m,u): 8 bytes
#pragma unroll
    for (int ms = 0; ms < 4; ++ms)
#pragma unroll
        for (int h = 0; h < 2; ++h)
#pragma unroll
            for (int j = 0; j < 4; ++j) {
                size_t mm = (size_t)(m0 + ms * 16 + ((l >> 4) << 2) + j);
                int u = w * 32 + h * 16 + (l & 15);
                unsigned int g0 = f2bf(acc[ms][0 + h][j]);
                unsigned int g1 = f2bf(acc[ms][2 + h][j]);
                unsigned int g2 = f2bf(acc[ms][4 + h][j]);
                unsigned int g3 = f2bf(acc[ms][6 + h][j]);
                uint2 v;
                v.x = g0 | (g1 << 16);
                v.y = g2 | (g3 << 16);
                *reinterpret_cast<uint2*>(zx + mm * 1024 + (size_t)u * 4) = v;
            }
}

// ---------------------------------------------------------------------------
// Scan. 8 blocks x 512 threads; block owns batches [b0, b0+16), all 256 U-cols.
// FUSED=1: no precomputed zx; also streams W-pack and stages x_t per step.
// ---------------------------------------------------------------------------
template <int FUSED>
__global__ __launch_bounds__(512, 2) void lstm_scan(
    const float* __restrict__ x,
    const float* __restrict__ h0, const float* __restrict__ c0,
    const float* __restrict__ bfv, const float* __restrict__ biv,
    const float* __restrict__ bcv, const float* __restrict__ bov,
    const short* __restrict__ upack, const short* __restrict__ wpack,
    const short* __restrict__ zx, float* __restrict__ out)
{
    __shared__ short hA[4096];   // A-fragments of h (bf16), 8 ks chunks
    __shared__ short xA[4096];   // A-fragments of x_t (FUSED only)

    const int tid = threadIdx.x;
    const int w = tid >> 6, l = tid & 63;
    const int b0 = blockIdx.x * 16;
    const int col = l & 15, rg = l >> 4;
    const size_t HALL = (size_t)B_ * T_ * U_;

    float bias[4][2];
#pragma unroll
    for (int h = 0; h < 2; ++h) {
        int u = w * 32 + h * 16 + col;
        bias[0][h] = bfv[u]; bias[1][h] = biv[u];
        bias[2][h] = bcv[u]; bias[3][h] = bov[u];
    }
    float cst[2][4];
#pragma unroll
    for (int h = 0; h < 2; ++h)
#pragma unroll
        for (int j = 0; j < 4; ++j)
            cst[h][j] = c0[(size_t)(b0 + rg * 4 + j) * 256 + (w * 32 + h * 16 + col)];

    // stage h0 as A-fragments (wave w stages ks-chunk w)
    {
        int ks = w;
        int bb = b0 + col;
        int k = ks * 32 + rg * 8;
        const float* s = h0 + (size_t)bb * 256 + k;
        float4 v0 = *reinterpret_cast<const float4*>(s);
        float4 v1 = *reinterpret_cast<const float4*>(s + 4);
        short8 fr;
        fr[0] = (short)f2bf(v0.x); fr[1] = (short)f2bf(v0.y);
        fr[2] = (short)f2bf(v0.z); fr[3] = (short)f2bf(v0.w);
        fr[4] = (short)f2bf(v1.x); fr[5] = (short)f2bf(v1.y);
        fr[6] = (short)f2bf(v1.z); fr[7] = (short)f2bf(v1.w);
        *reinterpret_cast<short8*>(&hA[ks * 512 + l * 8]) = fr;
    }
    __syncthreads();

    const short* baseU = upack + (size_t)w * 64 * 512;
    const short* baseW = wpack + (size_t)w * 64 * 512;

#pragma unroll 1
    for (int t = 0; t < T_; ++t) {
        float4v acc[8];
#pragma unroll
        for (int i = 0; i < 8; ++i) acc[i] = (float4v){0.f, 0.f, 0.f, 0.f};

        uint2 zxv[2][4];
        if constexpr (!FUSED) {
            // prefetch this step's input projections (independent of hA)
#pragma unroll
            for (int h = 0; h < 2; ++h)
#pragma unroll
                for (int j = 0; j < 4; ++j) {
                    size_t mm = (size_t)(b0 + rg * 4 + j) * T_ + t;
                    int u = w * 32 + h * 16 + col;
                    zxv[h][j] = *reinterpret_cast<const uint2*>(zx + mm * 1024 + (size_t)u * 4);
                }
        } else {
            int bb = b0 + col;
            int k = w * 32 + rg * 8;
            const float* s = x + ((size_t)bb * T_ + t) * 256 + k;
            float4 v0 = *reinterpret_cast<const float4*>(s);
            float4 v1 = *reinterpret_cast<const float4*>(s + 4);
            short8 fr;
            fr[0] = (short)f2bf(v0.x); fr[1] = (short)f2bf(v0.y);
            fr[2] = (short)f2bf(v0.z); fr[3] = (short)f2bf(v0.w);
            fr[4] = (short)f2bf(v1.x); fr[5] = (short)f2bf(v1.y);
            fr[6] = (short)f2bf(v1.z); fr[7] = (short)f2bf(v1.w);
            *reinterpret_cast<short8*>(&xA[w * 512 + l * 8]) = fr;
            __syncthreads();
        }

        // recurrent GEMM: stream U-fragments from L2
#pragma unroll
        for (int ks = 0; ks < 8; ++ks) {
            short8 a = *reinterpret_cast<const short8*>(&hA[ks * 512 + l * 8]);
#pragma unroll
            for (int c8 = 0; c8 < 8; ++c8) {
                short8 bfr = *reinterpret_cast<const short8*>(baseU + (size_t)(ks * 8 + c8) * 512 + l * 8);
                acc[c8] = __builtin_amdgcn_mfma_f32_16x16x32_bf16(a, bfr, acc[c8], 0, 0, 0);
            }
        }
        if constexpr (FUSED) {
#pragma unroll
            for (int ks = 0; ks < 8; ++ks) {
                short8 a = *reinterpret_cast<const short8*>(&xA[ks * 512 + l * 8]);
#pragma unroll
                for (int c8 = 0; c8 < 8; ++c8) {
                    short8 bfr = *reinterpret_cast<const short8*>(baseW + (size_t)(ks * 8 + c8) * 512 + l * 8);
                    acc[c8] = __builtin_amdgcn_mfma_f32_16x16x32_bf16(a, bfr, acc[c8], 0, 0, 0);
                }
            }
        }
        __syncthreads();   // all hA/xA reads complete before restage

        // elementwise: lane holds all 4 gates of its (b,u) pairs
#pragma unroll
        for (int h = 0; h < 2; ++h)
#pragma unroll
            for (int j = 0; j < 4; ++j) {
                float zf = acc[0 + h][j] + bias[0][h];
                float zi = acc[2 + h][j] + bias[1][h];
                float zc = acc[4 + h][j] + bias[2][h];
                float zo = acc[6 + h][j] + bias[3][h];
                if constexpr (!FUSED) {
                    uint2 v = zxv[h][j];
                    zf += bf2f(v.x & 0xffffu);
                    zi += bf2f(v.x >> 16);
                    zc += bf2f(v.y & 0xffffu);
                    zo += bf2f(v.y >> 16);
                }
                float fg = sigm(zf), ig = sigm(zi), og = sigm(zo);
                float cg = tanh_f(zc);
                float cn = fg * cst[h][j] + ig * cg;
                cst[h][j] = cn;
                float hn = og * tanh_f(cn);

                int bb = b0 + rg * 4 + j;
                int u = w * 32 + h * 16 + col;
                out[((size_t)bb * T_ + t) * 256 + u] = hn;
                if (t == T_ - 1) {
                    out[HALL + (size_t)bb * 256 + u] = hn;
                    out[HALL + (size_t)B_ * U_ + (size_t)bb * 256 + u] = cn;
                }
                // restage h into A-fragment layout (k-index = u)
                int ks2 = u >> 5;
                int s2 = (rg * 4 + j) + 16 * ((u >> 3) & 3);
                hA[ks2 * 512 + s2 * 8 + (u & 7)] = (short)f2bf(hn);
            }
        __syncthreads();   // hA ready for t+1
    }
}

extern "C" void kernel_launch(void* const* d_in, const int* in_sizes, int n_in,
                              void* d_out, int out_size, void* d_ws, size_t ws_size,
                              hipStream_t stream) {
    const float* x  = (const float*)d_in[0];
    const float* h0 = (const float*)d_in[1];
    const float* c0 = (const float*)d_in[2];
    const float* Wf = (const float*)d_in[3];
    const float* Uf = (const float*)d_in[4];
    const float* bf = (const float*)d_in[5];
    const float* Wi = (const float*)d_in[6];
    const float* Ui = (const float*)d_in[7];
    const float* bi = (const float*)d_in[8];
    const float* Wc = (const float*)d_in[9];
    const float* Uc = (const float*)d_in[10];
    const float* bc = (const float*)d_in[11];
    const float* Wo = (const float*)d_in[12];
    const float* Uo = (const float*)d_in[13];
    const float* bo = (const float*)d_in[14];

    short* ws    = (short*)d_ws;
    short* upack = ws;                 // 512 KB
    short* wpack = ws + 262144;        // 512 KB
    short* zx    = ws + 524288;        // 268.4 MB (bf16 [M][U][4])

    const size_t need = 1048576ull + (size_t)B_ * T_ * U_ * 4 * 2;
    const bool fused = ws_size < need;

    hipLaunchKernelGGL(pack_kernel, dim3(256), dim3(256), 0, stream,
                       Uf, Ui, Uc, Uo, Wf, Wi, Wc, Wo, ws);

    float* out = (float*)d_out;
    if (!fused) {
        hipLaunchKernelGGL(proj_kernel, dim3((B_ * T_) / 64), dim3(512), 0, stream,
                           x, wpack, zx);
        hipLaunchKernelGGL((lstm_scan<0>), dim3(8), dim3(512), 0, stream,
                           x, h0, c0, bf, bi, bc, bo, upack, wpack, zx, out);
    } else {
        hipLaunchKernelGGL((lstm_scan<1>), dim3(8), dim3(512), 0, stream,
                           x, h0, c0, bf, bi, bc, bo, upack, wpack, zx, out);
    }
}

// Round 2
// 5146.010 us; speedup vs baseline: 1.7911x; 1.7911x over previous
//
#include <hip/hip_runtime.h>
#include <hip/hip_bf16.h>

// CustomLSTM: B=128, T=1024, D=256, U=256, fp32 in/out.
// Round 2: CU-resident recurrent weights.
//  - pack_kernel: repack U*/W* fp32 -> bf16 MFMA B-fragment chunks in d_ws.
//  - proj_kernel: zx[t][b][u][4gates] (bf16, bias folded in fp32) = x @ W* + b.
//  - lstm_scan_res: 8 blocks x 16 batches. Per-wave 64 weight chunks:
//      46 chunks persistent in VGPRs (184 regs), 18 chunks in LDS (144 KB).
//      Per step: zero global weight traffic; read 32 KB zx (contiguous,
//      time-major), 64 MFMAs/wave, in-lane fp32 LSTM elementwise,
//      restage h via 8 KB LDS.
// No inter-block communication anywhere.

#define B_ 128
#define T_ 1024
#define D_ 256
#define U_ 256

#define NLDS 18          // chunks per wave in LDS
#define NREG 46          // chunks per wave in VGPRs  (NLDS+NREG = 64)

using short8  = __attribute__((ext_vector_type(8))) short;   // 8 bf16 (4 VGPRs)
using float4v = __attribute__((ext_vector_type(4))) float;   // 4 fp32 acc

__device__ inline unsigned short f2bf(float f) {
    unsigned int u = __float_as_uint(f);
    unsigned int r = (u + 0x7FFFu + ((u >> 16) & 1u)) >> 16;
    return (unsigned short)r;
}
__device__ inline float bf2f(unsigned int v) { return __uint_as_float(v << 16); }
__device__ inline float sigm(float z)  { return 1.0f / (1.0f + __expf(-z)); }
__device__ inline float tanh_f(float z){ float e = __expf(2.0f * z); return 1.0f - 2.0f / (e + 1.0f); }

// ---------------------------------------------------------------------------
// Pack 8 matrices [256][256] fp32 (row k, col u) into bf16 MFMA B-fragments.
// chunk = (w*8 + ks)*8 + g*2 + h ; chunk = 512 shorts (64 lanes x 8).
// Lane l of chunk holds  M[k = ks*32 + (l>>4)*8 + j][u = w*32 + h*16 + (l&15)].
// pack0 (offset 0 shorts)      = Uf,Ui,Uc,Uo   (recurrent)
// pack1 (offset 262144 shorts) = Wf,Wi,Wc,Wo   (input proj)
// ---------------------------------------------------------------------------
__global__ __launch_bounds__(256) void pack_kernel(
    const float* __restrict__ Uf, const float* __restrict__ Ui,
    const float* __restrict__ Uc, const float* __restrict__ Uo,
    const float* __restrict__ Wf, const float* __restrict__ Wi,
    const float* __restrict__ Wc, const float* __restrict__ Wo,
    short* __restrict__ ws)
{
    int q = blockIdx.x * 256 + threadIdx.x;      // 0..65535
    int p     = q >> 15;                          // 0: U-pack, 1: W-pack
    int rem   = q & 32767;
    int chunk = rem >> 6;                         // 0..511
    int l     = rem & 63;
    int c8 = chunk & 7;
    int g  = c8 >> 1;
    int h  = c8 & 1;
    int ks = (chunk >> 3) & 7;
    int w  = chunk >> 6;

    const float* mats[8] = {Uf, Ui, Uc, Uo, Wf, Wi, Wc, Wo};
    const float* M = mats[p * 4 + g];

    int u = w * 32 + h * 16 + (l & 15);
    int k = ks * 32 + ((l >> 4) << 3);
    const float* s = M + (size_t)k * 256 + u;

    short8 fr;
#pragma unroll
    for (int j = 0; j < 8; ++j) fr[j] = (short)f2bf(s[(size_t)j * 256]);

    short* dst = ws + (size_t)p * 262144 + (size_t)chunk * 512 + l * 8;
    *reinterpret_cast<short8*>(dst) = fr;
}

// ---------------------------------------------------------------------------
// proj: zx[t][b][u][g] (bf16, g minor, bias folded) = sum_k x[b][t][k]*W_g[k][u] + b_g[u]
// M-tile = 64 rows per block; streams W-pack fragments from L2.
// ---------------------------------------------------------------------------
__global__ __launch_bounds__(512, 2) void proj_kernel(
    const float* __restrict__ x, const short* __restrict__ wpack,
    const float* __restrict__ bfv, const float* __restrict__ biv,
    const float* __restrict__ bcv, const float* __restrict__ bov,
    short* __restrict__ zx)
{
    __shared__ short aF[4 * 8 * 512];  // 4 M-sub x 8 ks chunks (32KB)
    const int tid = threadIdx.x;
    const int w = tid >> 6, l = tid & 63;
    const long m0 = (long)blockIdx.x * 64;

    // stage A fragments: x rows m0..m0+63, bf16
#pragma unroll
    for (int rep = 0; rep < 4; ++rep) {
        int slot = tid + rep * 512;      // 0..2047
        int ms = slot >> 9;
        int rem = slot & 511;
        int ks = rem >> 6;
        int ll = rem & 63;
        long mm = m0 + ms * 16 + (ll & 15);
        int k = ks * 32 + ((ll >> 4) << 3);
        const float* s = x + (size_t)mm * 256 + k;
        float4 v0 = *reinterpret_cast<const float4*>(s);
        float4 v1 = *reinterpret_cast<const float4*>(s + 4);
        short8 fr;
        fr[0] = (short)f2bf(v0.x); fr[1] = (short)f2bf(v0.y);
        fr[2] = (short)f2bf(v0.z); fr[3] = (short)f2bf(v0.w);
        fr[4] = (short)f2bf(v1.x); fr[5] = (short)f2bf(v1.y);
        fr[6] = (short)f2bf(v1.z); fr[7] = (short)f2bf(v1.w);
        *reinterpret_cast<short8*>(&aF[(ms * 8 + ks) * 512 + ll * 8]) = fr;
    }
    __syncthreads();

    float4v acc[4][8];
#pragma unroll
    for (int ms = 0; ms < 4; ++ms)
#pragma unroll
        for (int c8 = 0; c8 < 8; ++c8) acc[ms][c8] = (float4v){0.f, 0.f, 0.f, 0.f};

    const short* base = wpack + (size_t)w * 64 * 512;
#pragma unroll
    for (int ks = 0; ks < 8; ++ks) {
        short8 a[4];
#pragma unroll
        for (int ms = 0; ms < 4; ++ms)
            a[ms] = *reinterpret_cast<const short8*>(&aF[(ms * 8 + ks) * 512 + l * 8]);
#pragma unroll
        for (int c8 = 0; c8 < 8; ++c8) {
            short8 bfr = *reinterpret_cast<const short8*>(base + (size_t)(ks * 8 + c8) * 512 + l * 8);
#pragma unroll
            for (int ms = 0; ms < 4; ++ms)
                acc[ms][c8] = __builtin_amdgcn_mfma_f32_16x16x32_bf16(a[ms], bfr, acc[ms][c8], 0, 0, 0);
        }
    }

    // write zx: 4 gates packed per (m,u): 8 bytes; bias folded in fp32.
#pragma unroll
    for (int ms = 0; ms < 4; ++ms)
#pragma unroll
        for (int h = 0; h < 2; ++h)
#pragma unroll
            for (int j = 0; j < 4; ++j) {
                size_t mm = (size_t)(m0 + ms * 16 + ((l >> 4) << 2) + j);
                int u = w * 32 + h * 16 + (l & 15);
                size_t b = mm >> 10;          // mm = b*T + t
                size_t t = mm & 1023;
                unsigned int g0 = f2bf(acc[ms][0 + h][j] + bfv[u]);
                unsigned int g1 = f2bf(acc[ms][2 + h][j] + biv[u]);
                unsigned int g2 = f2bf(acc[ms][4 + h][j] + bcv[u]);
                unsigned int g3 = f2bf(acc[ms][6 + h][j] + bov[u]);
                uint2 v;
                v.x = g0 | (g1 << 16);
                v.y = g2 | (g3 << 16);
                *reinterpret_cast<uint2*>(zx + (t * B_ + b) * 1024 + (size_t)u * 4) = v;
            }
}

// ---------------------------------------------------------------------------
// Resident scan. 8 blocks x 512 threads; block owns batches [b0, b0+16).
// Per-wave weights: chunks q in [0,NLDS) live in LDS, q in [NLDS,64) in VGPRs.
// ---------------------------------------------------------------------------
__global__ __launch_bounds__(512, 2) void lstm_scan_res(
    const float* __restrict__ h0, const float* __restrict__ c0,
    const short* __restrict__ upack, const short* __restrict__ zx,
    float* __restrict__ out)
{
    __shared__ short wlds[NLDS * 8 * 512];   // 144 KB weight chunks
    __shared__ short hA[4096];               // 8 KB h A-fragments (bf16)

    const int tid = threadIdx.x;
    const int w = tid >> 6, l = tid & 63;
    const int b0 = blockIdx.x * 16;
    const int col = l & 15, rg = l >> 4;
    const size_t HALL = (size_t)B_ * T_ * U_;

    // one-time: stage this wave's LDS chunks and load its register chunks
    const short* baseU = upack + (size_t)w * 64 * 512 + (size_t)l * 8;
#pragma unroll
    for (int q = 0; q < NLDS; ++q)
        *reinterpret_cast<short8*>(&wlds[((size_t)w * NLDS + q) * 512 + l * 8]) =
            *reinterpret_cast<const short8*>(baseU + (size_t)q * 512);
    short8 wreg[NREG];
#pragma unroll
    for (int r = 0; r < NREG; ++r)
        wreg[r] = *reinterpret_cast<const short8*>(baseU + (size_t)(NLDS + r) * 512);

    float cst[2][4];
#pragma unroll
    for (int h = 0; h < 2; ++h)
#pragma unroll
        for (int j = 0; j < 4; ++j)
            cst[h][j] = c0[(size_t)(b0 + rg * 4 + j) * 256 + (w * 32 + h * 16 + col)];

    // stage h0 as A-fragments (wave w stages ks-chunk w)
    {
        int ks = w;
        int bb = b0 + col;
        int k = ks * 32 + rg * 8;
        const float* s = h0 + (size_t)bb * 256 + k;
        float4 v0 = *reinterpret_cast<const float4*>(s);
        float4 v1 = *reinterpret_cast<const float4*>(s + 4);
        short8 fr;
        fr[0] = (short)f2bf(v0.x); fr[1] = (short)f2bf(v0.y);
        fr[2] = (short)f2bf(v0.z); fr[3] = (short)f2bf(v0.w);
        fr[4] = (short)f2bf(v1.x); fr[5] = (short)f2bf(v1.y);
        fr[6] = (short)f2bf(v1.z); fr[7] = (short)f2bf(v1.w);
        *reinterpret_cast<short8*>(&hA[ks * 512 + l * 8]) = fr;
    }
    __syncthreads();

#pragma unroll 1
    for (int t = 0; t < T_; ++t) {
        // prefetch this step's input projections (independent of hA)
        uint2 zxv[2][4];
#pragma unroll
        for (int h = 0; h < 2; ++h)
#pragma unroll
            for (int j = 0; j < 4; ++j) {
                size_t bb = (size_t)(b0 + rg * 4 + j);
                int u = w * 32 + h * 16 + col;
                zxv[h][j] = *reinterpret_cast<const uint2*>(
                    zx + ((size_t)t * B_ + bb) * 1024 + (size_t)u * 4);
            }

        float4v acc[8];
#pragma unroll
        for (int i = 0; i < 8; ++i) acc[i] = (float4v){0.f, 0.f, 0.f, 0.f};

        // recurrent GEMM: weights from VGPRs + LDS only
#pragma unroll
        for (int ks = 0; ks < 8; ++ks) {
            short8 a = *reinterpret_cast<const short8*>(&hA[ks * 512 + l * 8]);
#pragma unroll
            for (int c8 = 0; c8 < 8; ++c8) {
                const int q = ks * 8 + c8;
                short8 bfr;
                if (q < NLDS)
                    bfr = *reinterpret_cast<const short8*>(
                        &wlds[((size_t)w * NLDS + q) * 512 + l * 8]);
                else
                    bfr = wreg[q - NLDS];
                acc[c8] = __builtin_amdgcn_mfma_f32_16x16x32_bf16(a, bfr, acc[c8], 0, 0, 0);
            }
        }
        __syncthreads();   // all hA reads complete before restage

        // elementwise: lane holds all 4 gates of its (b,u) pairs
#pragma unroll
        for (int h = 0; h < 2; ++h)
#pragma unroll
            for (int j = 0; j < 4; ++j) {
                uint2 v = zxv[h][j];
                float zf = acc[0 + h][j] + bf2f(v.x & 0xffffu);
                float zi = acc[2 + h][j] + bf2f(v.x >> 16);
                float zc = acc[4 + h][j] + bf2f(v.y & 0xffffu);
                float zo = acc[6 + h][j] + bf2f(v.y >> 16);
                float fg = sigm(zf), ig = sigm(zi), og = sigm(zo);
                float cg = tanh_f(zc);
                float cn = fg * cst[h][j] + ig * cg;
                cst[h][j] = cn;
                float hn = og * tanh_f(cn);

                int bb = b0 + rg * 4 + j;
                int u = w * 32 + h * 16 + col;
                out[((size_t)bb * T_ + t) * 256 + u] = hn;
                if (t == T_ - 1) {
                    out[HALL + (size_t)bb * 256 + u] = hn;
                    out[HALL + (size_t)B_ * U_ + (size_t)bb * 256 + u] = cn;
                }
                // restage h into A-fragment layout (k-index = u)
                int ks2 = u >> 5;
                int s2 = (rg * 4 + j) + 16 * ((u >> 3) & 3);
                hA[ks2 * 512 + s2 * 8 + (u & 7)] = (short)f2bf(hn);
            }
        __syncthreads();   // hA ready for t+1
    }
}

// ---------------------------------------------------------------------------
// Fallback fused scan (workspace too small for zx): streams U and W packs
// from L2 every step. Slow but correct.
// ---------------------------------------------------------------------------
__global__ __launch_bounds__(512, 2) void lstm_scan_fused(
    const float* __restrict__ x,
    const float* __restrict__ h0, const float* __restrict__ c0,
    const float* __restrict__ bfv, const float* __restrict__ biv,
    const float* __restrict__ bcv, const float* __restrict__ bov,
    const short* __restrict__ upack, const short* __restrict__ wpack,
    float* __restrict__ out)
{
    __shared__ short hA[4096];
    __shared__ short xA[4096];

    const int tid = threadIdx.x;
    const int w = tid >> 6, l = tid & 63;
    const int b0 = blockIdx.x * 16;
    const int col = l & 15, rg = l >> 4;
    const size_t HALL = (size_t)B_ * T_ * U_;

    float bias[4][2];
#pragma unroll
    for (int h = 0; h < 2; ++h) {
        int u = w * 32 + h * 16 + col;
        bias[0][h] = bfv[u]; bias[1][h] = biv[u];
        bias[2][h] = bcv[u]; bias[3][h] = bov[u];
    }
    float cst[2][4];
#pragma unroll
    for (int h = 0; h < 2; ++h)
#pragma unroll
        for (int j = 0; j < 4; ++j)
            cst[h][j] = c0[(size_t)(b0 + rg * 4 + j) * 256 + (w * 32 + h * 16 + col)];

    {
        int ks = w;
        int bb = b0 + col;
        int k = ks * 32 + rg * 8;
        const float* s = h0 + (size_t)bb * 256 + k;
        float4 v0 = *reinterpret_cast<const float4*>(s);
        float4 v1 = *reinterpret_cast<const float4*>(s + 4);
        short8 fr;
        fr[0] = (short)f2bf(v0.x); fr[1] = (short)f2bf(v0.y);
        fr[2] = (short)f2bf(v0.z); fr[3] = (short)f2bf(v0.w);
        fr[4] = (short)f2bf(v1.x); fr[5] = (short)f2bf(v1.y);
        fr[6] = (short)f2bf(v1.z); fr[7] = (short)f2bf(v1.w);
        *reinterpret_cast<short8*>(&hA[ks * 512 + l * 8]) = fr;
    }
    __syncthreads();

    const short* baseU = upack + (size_t)w * 64 * 512;
    const short* baseW = wpack + (size_t)w * 64 * 512;

#pragma unroll 1
    for (int t = 0; t < T_; ++t) {
        float4v acc[8];
#pragma unroll
        for (int i = 0; i < 8; ++i) acc[i] = (float4v){0.f, 0.f, 0.f, 0.f};

        {
            int bb = b0 + col;
            int k = w * 32 + rg * 8;
            const float* s = x + ((size_t)bb * T_ + t) * 256 + k;
            float4 v0 = *reinterpret_cast<const float4*>(s);
            float4 v1 = *reinterpret_cast<const float4*>(s + 4);
            short8 fr;
            fr[0] = (short)f2bf(v0.x); fr[1] = (short)f2bf(v0.y);
            fr[2] = (short)f2bf(v0.z); fr[3] = (short)f2bf(v0.w);
            fr[4] = (short)f2bf(v1.x); fr[5] = (short)f2bf(v1.y);
            fr[6] = (short)f2bf(v1.z); fr[7] = (short)f2bf(v1.w);
            *reinterpret_cast<short8*>(&xA[w * 512 + l * 8]) = fr;
            __syncthreads();
        }

#pragma unroll
        for (int ks = 0; ks < 8; ++ks) {
            short8 a = *reinterpret_cast<const short8*>(&hA[ks * 512 + l * 8]);
#pragma unroll
            for (int c8 = 0; c8 < 8; ++c8) {
                short8 bfr = *reinterpret_cast<const short8*>(baseU + (size_t)(ks * 8 + c8) * 512 + l * 8);
                acc[c8] = __builtin_amdgcn_mfma_f32_16x16x32_bf16(a, bfr, acc[c8], 0, 0, 0);
            }
        }
#pragma unroll
        for (int ks = 0; ks < 8; ++ks) {
            short8 a = *reinterpret_cast<const short8*>(&xA[ks * 512 + l * 8]);
#pragma unroll
            for (int c8 = 0; c8 < 8; ++c8) {
                short8 bfr = *reinterpret_cast<const short8*>(baseW + (size_t)(ks * 8 + c8) * 512 + l * 8);
                acc[c8] = __builtin_amdgcn_mfma_f32_16x16x32_bf16(a, bfr, acc[c8], 0, 0, 0);
            }
        }
        __syncthreads();

#pragma unroll
        for (int h = 0; h < 2; ++h)
#pragma unroll
            for (int j = 0; j < 4; ++j) {
                float zf = acc[0 + h][j] + bias[0][h];
                float zi = acc[2 + h][j] + bias[1][h];
                float zc = acc[4 + h][j] + bias[2][h];
                float zo = acc[6 + h][j] + bias[3][h];
                float fg = sigm(zf), ig = sigm(zi), og = sigm(zo);
                float cg = tanh_f(zc);
                float cn = fg * cst[h][j] + ig * cg;
                cst[h][j] = cn;
                float hn = og * tanh_f(cn);

                int bb = b0 + rg * 4 + j;
                int u = w * 32 + h * 16 + col;
                out[((size_t)bb * T_ + t) * 256 + u] = hn;
                if (t == T_ - 1) {
                    out[HALL + (size_t)bb * 256 + u] = hn;
                    out[HALL + (size_t)B_ * U_ + (size_t)bb * 256 + u] = cn;
                }
                int ks2 = u >> 5;
                int s2 = (rg * 4 + j) + 16 * ((u >> 3) & 3);
                hA[ks2 * 512 + s2 * 8 + (u & 7)] = (short)f2bf(hn);
            }
        __syncthreads();
    }
}

extern "C" void kernel_launch(void* const* d_in, const int* in_sizes, int n_in,
                              void* d_out, int out_size, void* d_ws, size_t ws_size,
                              hipStream_t stream) {
    const float* x  = (const float*)d_in[0];
    const float* h0 = (const float*)d_in[1];
    const float* c0 = (const float*)d_in[2];
    const float* Wf = (const float*)d_in[3];
    const float* Uf = (const float*)d_in[4];
    const float* bf = (const float*)d_in[5];
    const float* Wi = (const float*)d_in[6];
    const float* Ui = (const float*)d_in[7];
    const float* bi = (const float*)d_in[8];
    const float* Wc = (const float*)d_in[9];
    const float* Uc = (const float*)d_in[10];
    const float* bc = (const float*)d_in[11];
    const float* Wo = (const float*)d_in[12];
    const float* Uo = (const float*)d_in[13];
    const float* bo = (const float*)d_in[14];

    short* ws    = (short*)d_ws;
    short* upack = ws;                 // 512 KB
    short* wpack = ws + 262144;        // 512 KB
    short* zx    = ws + 524288;        // 268.4 MB (bf16 [T][B][U][4])

    const size_t need = 1048576ull + (size_t)B_ * T_ * U_ * 4 * 2;
    const bool fused = ws_size < need;

    hipLaunchKernelGGL(pack_kernel, dim3(256), dim3(256), 0, stream,
                       Uf, Ui, Uc, Uo, Wf, Wi, Wc, Wo, ws);

    float* out = (float*)d_out;
    if (!fused) {
        hipLaunchKernelGGL(proj_kernel, dim3((B_ * T_) / 64), dim3(512), 0, stream,
                           x, wpack, bf, bi, bc, bo, zx);
        hipLaunchKernelGGL(lstm_scan_res, dim3(8), dim3(512), 0, stream,
                           h0, c0, upack, zx, out);
    } else {
        hipLaunchKernelGGL(lstm_scan_fused, dim3(8), dim3(512), 0, stream,
                           x, h0, c0, bf, bi, bc, bo, upack, wpack, out);
    }
}